// Round 17
// baseline (9329.057 us; speedup 1.0000x reference)
//
#include <hip/hip_runtime.h>

// Problem dims (fixed)
constexpr int Bb = 32;    // batch
constexpr int Tt = 1024;  // time steps
constexpr int Hh = 1024;  // hidden
constexpr int Di = 512;   // input dim
constexpr int Do = 512;   // output dim
constexpr int TGSZ = Bb * Hh;  // dwords per tagged h buffer slot
constexpr int BbHh = Bb * Hh;

using bf16x8 = __attribute__((ext_vector_type(8))) short;
using f32x4  = __attribute__((ext_vector_type(4))) float;

__device__ __forceinline__ f32x4 mfma16(bf16x8 a, bf16x8 b, f32x4 c) {
  return __builtin_amdgcn_mfma_f32_16x16x32_bf16(a, b, c, 0, 0, 0);
}
__device__ __forceinline__ unsigned short f2bf(float f) {
  unsigned u = __builtin_bit_cast(unsigned, f);
  u += 0x7FFFu + ((u >> 16) & 1u);
  return (unsigned short)(u >> 16);
}
__device__ __forceinline__ float bf2f(unsigned short h) {
  unsigned u = ((unsigned)h) << 16;
  return __builtin_bit_cast(float, u);
}

// ---------------- fp32 -> bf16 bulk convert (for Wh) ----------------
__global__ __launch_bounds__(256) void cvt4_kernel(const float* __restrict__ s,
                                                   unsigned short* __restrict__ d) {
  int i = (blockIdx.x * 256 + threadIdx.x) * 4;
  float4 v = *(const float4*)(s + i);
  ushort4 u = { f2bf(v.x), f2bf(v.y), f2bf(v.z), f2bf(v.w) };
  *(ushort4*)(d + i) = u;
}

// ---------------- tagged-buffer init ----------------
// buf[0] = h_{-1}=0 with tag 0xFFFF (expected at t=0); buf[1],buf[2] = never-valid tag.
__global__ __launch_bounds__(256) void init_tags(unsigned* __restrict__ tg) {
  int i = blockIdx.x * 256 + threadIdx.x;
  tg[i] = (i < TGSZ) ? 0xFFFF0000u : 0xEEEE0000u;
}

// ---------------- GEMM: C[m][n] = sum_k A[m][k] * Bw[n][k] (+bias) ----------------
template <int MODE>
__global__ __launch_bounds__(256)
void gemm_kernel(const void* __restrict__ Ap, const float* __restrict__ Bw,
                 const float* __restrict__ bias1, const float* __restrict__ bias2,
                 void* __restrict__ Cp) {
  constexpr int K = (MODE == 0) ? Di : Hh;
  constexpr int BM = 64, BN = 64, BK = 64;
  __shared__ unsigned short As[BM][80];
  __shared__ unsigned short Bs[BN][80];

  const int m0 = blockIdx.x * BM;
  const int n0 = blockIdx.y * BN;
  const int tid = threadIdx.x;
  const int lane = tid & 63;
  const int wave = tid >> 6;
  const int wm = (wave & 1) * 32;
  const int wn = (wave >> 1) * 32;
  const int fr = lane & 15;
  const int kg = lane >> 4;

  f32x4 acc[2][2] = {};

  const int srow = tid >> 2;          // 0..63
  const int scb  = (tid & 3) * 16;    // 0,16,32,48

  for (int k0 = 0; k0 < K; k0 += BK) {
    if constexpr (MODE == 0) {
      const float* a = (const float*)Ap + (size_t)(m0 + srow) * K + k0 + scb;
#pragma unroll
      for (int q = 0; q < 4; ++q) {
        float4 v = ((const float4*)a)[q];
        ushort4 u = { f2bf(v.x), f2bf(v.y), f2bf(v.z), f2bf(v.w) };
        *(ushort4*)&As[srow][scb + q * 4] = u;
      }
    } else {
      const unsigned short* a = (const unsigned short*)Ap + (size_t)(m0 + srow) * K + k0 + scb;
      *(uint4*)&As[srow][scb]     = ((const uint4*)a)[0];
      *(uint4*)&As[srow][scb + 8] = ((const uint4*)a)[1];
    }
    {
      const float* b = Bw + (size_t)(n0 + srow) * K + k0 + scb;
#pragma unroll
      for (int q = 0; q < 4; ++q) {
        float4 v = ((const float4*)b)[q];
        ushort4 u = { f2bf(v.x), f2bf(v.y), f2bf(v.z), f2bf(v.w) };
        *(ushort4*)&Bs[srow][scb + q * 4] = u;
      }
    }
    __syncthreads();

#pragma unroll
    for (int kk = 0; kk < 2; ++kk) {
      const int kb = kk * 32 + kg * 8;
      bf16x8 af[2], bfr[2];
      af[0]  = *(const bf16x8*)&As[wm + fr][kb];
      af[1]  = *(const bf16x8*)&As[wm + 16 + fr][kb];
      bfr[0] = *(const bf16x8*)&Bs[wn + fr][kb];
      bfr[1] = *(const bf16x8*)&Bs[wn + 16 + fr][kb];
#pragma unroll
      for (int i = 0; i < 2; ++i)
#pragma unroll
        for (int j = 0; j < 2; ++j)
          acc[i][j] = mfma16(af[i], bfr[j], acc[i][j]);
    }
    __syncthreads();
  }

#pragma unroll
  for (int i = 0; i < 2; ++i) {
#pragma unroll
    for (int j = 0; j < 2; ++j) {
      const int n = n0 + wn + j * 16 + fr;
      float bv;
      if constexpr (MODE == 0) bv = bias1[n] + bias2[n];
      else                     bv = bias1[n];
#pragma unroll
      for (int q = 0; q < 4; ++q) {
        const int m = m0 + wm + i * 16 + kg * 4 + q;
        float v = acc[i][j][q] + bv;
        if constexpr (MODE == 0) {
          int bb = m >> 10, ttt = m & 1023;
          ((unsigned short*)Cp)[((size_t)ttt * Bb + bb) * Hh + n] = f2bf(v);
        } else {
          int bb = m & 31, ttt = m >> 5;
          ((float*)Cp)[((size_t)bb * Tt + ttt) * Do + n] = v;
        }
      }
    }
  }
}

// ---------------- sequential scan: R10 protocol + drain overlap ----------------
// 16 blocks x 512 threads: g = blockIdx>>3 (batch-group of 16), r = blockIdx&7
// (128 h-rows). h exchanged as LLC-homed tagged dwords (tag<<16 | bf16), 3-buffer
// rotation; the detecting load IS the data load. XCD-local paths abandoned (R14-16).
// R17 changes vs R10 (latency overlap, sync semantics untouched):
//  (1) hist stores DEFERRED one step (issued after next step's barrier) — their
//      scattered HBM RMW no longer sits inside the poll's in-order vmcnt(0) drain;
//  (2) xp prefetch for t+1 issued post-stage (retires under MFMA);
//  (3) double LDS panel -> ONE barrier/step (WAR-safe: rewriting panel[p] requires
//      passing the next barrier, which requires all waves past their MFMA on p).
// Epilogue issues ONLY the 4 tagged sc0sc1 stores before the next poll.
// Spins BOUNDED (8192): wrong data on timeout, never a hang.
__global__ __launch_bounds__(512, 2)
void scan_kernel(const unsigned short* __restrict__ Whb,  // bf16 [H][H]
                 const unsigned short* __restrict__ xp,   // bf16 [T][B][H]
                 unsigned short* __restrict__ hist,       // bf16 [T][B][H]
                 unsigned* __restrict__ tg) {             // tagged [3][B][H]
  __shared__ unsigned short panel[2][16 * 1024];  // double-buffered, XOR-swizzled

  const int tid = threadIdx.x;
  const int g = blockIdx.x >> 3;
  const int r = blockIdx.x & 7;
  const int wave = tid >> 6;
  const int lane = tid & 63;
  const int nloc = lane & 15;
  const int kgrp = lane >> 4;
  const int hrow = r * 128 + wave * 16 + nloc;   // this lane's h output row
  const int gb0 = g * 16;
  const int xmask = (nloc & 7) << 3;

  // preload Wh fragments via opaque asm loads (proven-safe R10 form)
  bf16x8 wf[32];
  {
    const unsigned short* wb = Whb + (size_t)hrow * Hh + kgrp * 8;
#pragma unroll
    for (int kk = 0; kk < 32; kk += 8) {
      const unsigned short* p = wb + kk * 32;
      asm volatile(
          "global_load_dwordx4 %0, %8, off\n\t"
          "global_load_dwordx4 %1, %8, off offset:64\n\t"
          "global_load_dwordx4 %2, %8, off offset:128\n\t"
          "global_load_dwordx4 %3, %8, off offset:192\n\t"
          "global_load_dwordx4 %4, %8, off offset:256\n\t"
          "global_load_dwordx4 %5, %8, off offset:320\n\t"
          "global_load_dwordx4 %6, %8, off offset:384\n\t"
          "global_load_dwordx4 %7, %8, off offset:448\n\t"
          "s_waitcnt vmcnt(0)"
          : "=&v"(wf[kk + 0]), "=&v"(wf[kk + 1]), "=&v"(wf[kk + 2]), "=&v"(wf[kk + 3]),
            "=&v"(wf[kk + 4]), "=&v"(wf[kk + 5]), "=&v"(wf[kk + 6]), "=&v"(wf[kk + 7])
          : "v"(p)
          : "memory");
    }
  }

  const int sb  = tid & 15;   // batch (within group) staged by this thread
  const int kc  = tid >> 4;   // 0..31: its 32-element K chunk
  const int sxs = (sb & 7) << 3;

  // prologue: xp for t=0; no deferred hist yet
  unsigned short xpv[4], hbp[4];
#pragma unroll
  for (int i = 0; i < 4; ++i)
    xpv[i] = xp[(size_t)(gb0 + kgrp * 4 + i) * Hh + hrow];

  for (int t = 0; t < Tt; ++t) {
    const int par = t % 3;
    const int nxt = (t + 1) % 3;
    unsigned short* pan = &panel[t & 1][0];

    // poll my 32-word chunk of h^{t-1} until every word carries tag t-1.
    // vmcnt(0) drains: tagged(t-1) acks + hist(t-2)/xp(t) issued pre-MFMA (mostly done).
    const unsigned exp = ((unsigned)t - 1u) & 0xFFFFu;
    const unsigned* src = tg + (size_t)par * TGSZ + (size_t)(gb0 + sb) * Hh + kc * 32;
    uint4 d0, d1, d2, d3, d4, d5, d6, d7;
    unsigned bad;
    int tries = 8192;
    do {
      asm volatile(
          "global_load_dwordx4 %0, %8, off sc0 sc1\n\t"
          "global_load_dwordx4 %1, %8, off offset:16 sc0 sc1\n\t"
          "global_load_dwordx4 %2, %8, off offset:32 sc0 sc1\n\t"
          "global_load_dwordx4 %3, %8, off offset:48 sc0 sc1\n\t"
          "global_load_dwordx4 %4, %8, off offset:64 sc0 sc1\n\t"
          "global_load_dwordx4 %5, %8, off offset:80 sc0 sc1\n\t"
          "global_load_dwordx4 %6, %8, off offset:96 sc0 sc1\n\t"
          "global_load_dwordx4 %7, %8, off offset:112 sc0 sc1\n\t"
          "s_waitcnt vmcnt(0)"
          : "=&v"(d0), "=&v"(d1), "=&v"(d2), "=&v"(d3),
            "=&v"(d4), "=&v"(d5), "=&v"(d6), "=&v"(d7)
          : "v"(src) : "memory");
      bad = 0;
#define CHK(v) bad |= ((v.x >> 16) ^ exp) | ((v.y >> 16) ^ exp) | \
                      ((v.z >> 16) ^ exp) | ((v.w >> 16) ^ exp)
      CHK(d0); CHK(d1); CHK(d2); CHK(d3); CHK(d4); CHK(d5); CHK(d6); CHK(d7);
#undef CHK
    } while (bad && --tries);

    // strip tags, pack to bf16 pairs, write swizzled LDS panel
    {
#define PK(a, b) (((a) & 0xFFFFu) | ((b) << 16))
      uint4 p0 = { PK(d0.x, d0.y), PK(d0.z, d0.w), PK(d1.x, d1.y), PK(d1.z, d1.w) };
      uint4 p1 = { PK(d2.x, d2.y), PK(d2.z, d2.w), PK(d3.x, d3.y), PK(d3.z, d3.w) };
      uint4 p2 = { PK(d4.x, d4.y), PK(d4.z, d4.w), PK(d5.x, d5.y), PK(d5.z, d5.w) };
      uint4 p3 = { PK(d6.x, d6.y), PK(d6.z, d6.w), PK(d7.x, d7.y), PK(d7.z, d7.w) };
#undef PK
      const int pb = sb * 1024, k0 = kc * 32;
      *(uint4*)&pan[pb + ((k0)      ^ sxs)] = p0;
      *(uint4*)&pan[pb + ((k0 + 8)  ^ sxs)] = p1;
      *(uint4*)&pan[pb + ((k0 + 16) ^ sxs)] = p2;
      *(uint4*)&pan[pb + ((k0 + 24) ^ sxs)] = p3;
    }
    __syncthreads();   // the ONE barrier: stage(t) visible to all before MFMA(t)

    // deferred hist stores for t-1 (overlap MFMA; drained by poll(t+1) when long done)
    if (t > 0) {
      const size_t tbp = (size_t)(t - 1) * BbHh;
#pragma unroll
      for (int i = 0; i < 4; ++i)
        hist[tbp + (size_t)(gb0 + kgrp * 4 + i) * Hh + hrow] = hbp[i];
    }
    // xp prefetch for t+1 (retires under MFMA)
    unsigned short xpn[4];
    if (t + 1 < Tt) {
      const size_t xb = (size_t)(t + 1) * BbHh + hrow;
#pragma unroll
      for (int i = 0; i < 4; ++i)
        xpn[i] = xp[xb + (size_t)(gb0 + kgrp * 4 + i) * Hh];
    }

    // MFMA: [16 batch] x [16 rows] over K=1024 (LDS-only; lgkmcnt, no vmcnt)
    f32x4 acc0 = {0.f, 0.f, 0.f, 0.f}, acc1 = {0.f, 0.f, 0.f, 0.f};
    const unsigned short* prow = pan + nloc * 1024;
#pragma unroll
    for (int kk = 0; kk < 32; kk += 2) {
      bf16x8 a0 = *(const bf16x8*)&prow[((kk)     * 32 + kgrp * 8) ^ xmask];
      bf16x8 a1 = *(const bf16x8*)&prow[((kk + 1) * 32 + kgrp * 8) ^ xmask];
      acc0 = mfma16(a0, wf[kk], acc0);
      acc1 = mfma16(a1, wf[kk + 1], acc1);
    }
    f32x4 acc = acc0 + acc1;

    // epilogue: sigmoid; publish ONLY the 4 tagged words (communication-critical)
    unsigned* dbase = tg + (size_t)nxt * TGSZ + hrow;
#pragma unroll
    for (int i = 0; i < 4; ++i) {
      const int mb = gb0 + kgrp * 4 + i;
      float pre = acc[i] + bf2f(xpv[i]);
      float h = 1.0f / (1.0f + __expf(-pre));
      unsigned short hb = f2bf(h);
      unsigned word = ((unsigned)t << 16) | (unsigned)hb;
      asm volatile("global_store_dword %0, %1, off sc0 sc1"
                   :: "v"(dbase + (size_t)mb * Hh), "v"(word) : "memory");
      hbp[i] = hb;
    }
#pragma unroll
    for (int i = 0; i < 4; ++i) xpv[i] = xpn[i];
    // no trailing barrier: next iteration stages the OTHER panel (WAR-safe, see header)
  }

  // final deferred hist stores (t = Tt-1)
  {
    const size_t tbp = (size_t)(Tt - 1) * BbHh;
#pragma unroll
    for (int i = 0; i < 4; ++i)
      hist[tbp + (size_t)(gb0 + kgrp * 4 + i) * Hh + hrow] = hbp[i];
  }
}

// ---------------- launch ----------------
extern "C" void kernel_launch(void* const* d_in, const int* in_sizes, int n_in,
                              void* d_out, int out_size, void* d_ws, size_t ws_size,
                              hipStream_t stream) {
  const float* x    = (const float*)d_in[0];
  const float* Wh_w = (const float*)d_in[1];
  const float* Wh_b = (const float*)d_in[2];
  const float* Wx_w = (const float*)d_in[3];
  const float* Wx_b = (const float*)d_in[4];
  const float* Wy_w = (const float*)d_in[5];
  const float* Wy_b = (const float*)d_in[6];

  char* ws = (char*)d_ws;
  constexpr size_t XP_OFF   = 0;                                     // bf16 [T][B][H] = 64 MiB
  constexpr size_t HIST_OFF = XP_OFF   + (size_t)Tt * Bb * Hh * 2;   // 64 MiB
  constexpr size_t WH_OFF   = HIST_OFF + (size_t)Tt * Bb * Hh * 2;   // 2 MiB
  constexpr size_t TG_OFF   = WH_OFF   + (size_t)Hh * Hh * 2;        // 384 KiB

  unsigned short* xp   = (unsigned short*)(ws + XP_OFF);
  unsigned short* hist = (unsigned short*)(ws + HIST_OFF);
  unsigned short* whb  = (unsigned short*)(ws + WH_OFF);
  unsigned*       tg   = (unsigned*)(ws + TG_OFF);

  // tagged-buffer init (fully rewrites all 3 slots every call — no memset needed)
  init_tags<<<dim3((3 * TGSZ) / 256), dim3(256), 0, stream>>>(tg);

  // Wh fp32 -> bf16
  cvt4_kernel<<<dim3((Hh * Hh) / (256 * 4)), dim3(256), 0, stream>>>(Wh_w, whb);

  // xp = x @ Wx^T + Wx_b + Wh_b   (stored [T][B][H] bf16)
  gemm_kernel<0><<<dim3((Bb * Tt) / 64, Hh / 64), dim3(256), 0, stream>>>(
      (const void*)x, Wx_w, Wx_b, Wh_b, (void*)xp);

  // sequential scan (cooperative; bounded spins make a plain launch safe fallback)
  {
    void* sargs[4] = { (void*)&whb, (void*)&xp, (void*)&hist, (void*)&tg };
    hipError_t ce = hipLaunchCooperativeKernel((const void*)scan_kernel, dim3(16), dim3(512),
                                               sargs, 0, stream);
    if (ce != hipSuccess) {
      scan_kernel<<<dim3(16), dim3(512), 0, stream>>>(whb, xp, hist, tg);
    }
  }

  // out = hist @ Wy^T + Wy_b  (fp32 [B][T][Do])
  gemm_kernel<1><<<dim3((Bb * Tt) / 64, Do / 64), dim3(256), 0, stream>>>(
      (const void*)hist, Wy_w, Wy_b, nullptr, d_out);
}

// Round 18
// 5858.880 us; speedup vs baseline: 1.5923x; 1.5923x over previous
//
#include <hip/hip_runtime.h>

// Problem dims (fixed)
constexpr int Bb = 32;    // batch
constexpr int Tt = 1024;  // time steps
constexpr int Hh = 1024;  // hidden
constexpr int Di = 512;   // input dim
constexpr int Do = 512;   // output dim
constexpr int TGSZ = Bb * Hh;  // dwords per tagged h buffer slot

using bf16x8 = __attribute__((ext_vector_type(8))) short;
using f32x4  = __attribute__((ext_vector_type(4))) float;

__device__ __forceinline__ f32x4 mfma16(bf16x8 a, bf16x8 b, f32x4 c) {
  return __builtin_amdgcn_mfma_f32_16x16x32_bf16(a, b, c, 0, 0, 0);
}
__device__ __forceinline__ unsigned short f2bf(float f) {
  unsigned u = __builtin_bit_cast(unsigned, f);
  u += 0x7FFFu + ((u >> 16) & 1u);
  return (unsigned short)(u >> 16);
}
__device__ __forceinline__ float bf2f(unsigned short h) {
  unsigned u = ((unsigned)h) << 16;
  return __builtin_bit_cast(float, u);
}

// ---------------- fp32 -> bf16 bulk convert (for Wh) ----------------
__global__ __launch_bounds__(256) void cvt4_kernel(const float* __restrict__ s,
                                                   unsigned short* __restrict__ d) {
  int i = (blockIdx.x * 256 + threadIdx.x) * 4;
  float4 v = *(const float4*)(s + i);
  ushort4 u = { f2bf(v.x), f2bf(v.y), f2bf(v.z), f2bf(v.w) };
  *(ushort4*)(d + i) = u;
}

// ---------------- tagged-buffer init ----------------
// buf[0] = h_{-1}=0 with tag 0xFFFF (expected at t=0); buf[1],buf[2] = never-valid tag.
__global__ __launch_bounds__(256) void init_tags(unsigned* __restrict__ tg) {
  int i = blockIdx.x * 256 + threadIdx.x;
  tg[i] = (i < TGSZ) ? 0xFFFF0000u : 0xEEEE0000u;
}

// ---------------- GEMM: C[m][n] = sum_k A[m][k] * Bw[n][k] (+bias) ----------------
template <int MODE>
__global__ __launch_bounds__(256)
void gemm_kernel(const void* __restrict__ Ap, const float* __restrict__ Bw,
                 const float* __restrict__ bias1, const float* __restrict__ bias2,
                 void* __restrict__ Cp) {
  constexpr int K = (MODE == 0) ? Di : Hh;
  constexpr int BM = 64, BN = 64, BK = 64;
  __shared__ unsigned short As[BM][80];
  __shared__ unsigned short Bs[BN][80];

  const int m0 = blockIdx.x * BM;
  const int n0 = blockIdx.y * BN;
  const int tid = threadIdx.x;
  const int lane = tid & 63;
  const int wave = tid >> 6;
  const int wm = (wave & 1) * 32;
  const int wn = (wave >> 1) * 32;
  const int fr = lane & 15;
  const int kg = lane >> 4;

  f32x4 acc[2][2] = {};

  const int srow = tid >> 2;          // 0..63
  const int scb  = (tid & 3) * 16;    // 0,16,32,48

  for (int k0 = 0; k0 < K; k0 += BK) {
    if constexpr (MODE == 0) {
      const float* a = (const float*)Ap + (size_t)(m0 + srow) * K + k0 + scb;
#pragma unroll
      for (int q = 0; q < 4; ++q) {
        float4 v = ((const float4*)a)[q];
        ushort4 u = { f2bf(v.x), f2bf(v.y), f2bf(v.z), f2bf(v.w) };
        *(ushort4*)&As[srow][scb + q * 4] = u;
      }
    } else {
      const unsigned short* a = (const unsigned short*)Ap + (size_t)(m0 + srow) * K + k0 + scb;
      *(uint4*)&As[srow][scb]     = ((const uint4*)a)[0];
      *(uint4*)&As[srow][scb + 8] = ((const uint4*)a)[1];
    }
    {
      const float* b = Bw + (size_t)(n0 + srow) * K + k0 + scb;
#pragma unroll
      for (int q = 0; q < 4; ++q) {
        float4 v = ((const float4*)b)[q];
        ushort4 u = { f2bf(v.x), f2bf(v.y), f2bf(v.z), f2bf(v.w) };
        *(ushort4*)&Bs[srow][scb + q * 4] = u;
      }
    }
    __syncthreads();

#pragma unroll
    for (int kk = 0; kk < 2; ++kk) {
      const int kb = kk * 32 + kg * 8;
      bf16x8 af[2], bfr[2];
      af[0]  = *(const bf16x8*)&As[wm + fr][kb];
      af[1]  = *(const bf16x8*)&As[wm + 16 + fr][kb];
      bfr[0] = *(const bf16x8*)&Bs[wn + fr][kb];
      bfr[1] = *(const bf16x8*)&Bs[wn + 16 + fr][kb];
#pragma unroll
      for (int i = 0; i < 2; ++i)
#pragma unroll
        for (int j = 0; j < 2; ++j)
          acc[i][j] = mfma16(af[i], bfr[j], acc[i][j]);
    }
    __syncthreads();
  }

#pragma unroll
  for (int i = 0; i < 2; ++i) {
#pragma unroll
    for (int j = 0; j < 2; ++j) {
      const int n = n0 + wn + j * 16 + fr;
      float bv;
      if constexpr (MODE == 0) bv = bias1[n] + bias2[n];
      else                     bv = bias1[n];
#pragma unroll
      for (int q = 0; q < 4; ++q) {
        const int m = m0 + wm + i * 16 + kg * 4 + q;
        float v = acc[i][j][q] + bv;
        if constexpr (MODE == 0) {
          int bb = m >> 10, ttt = m & 1023;
          ((unsigned short*)Cp)[((size_t)ttt * Bb + bb) * Hh + n] = f2bf(v);
        } else {
          int bb = m & 31, ttt = m >> 5;
          ((float*)Cp)[((size_t)bb * Tt + ttt) * Do + n] = v;
        }
      }
    }
  }
}

// ---------------- sequential scan ----------------
// 16 blocks x 512 threads: g = blockIdx>>3 (batch-group of 16), r = blockIdx&7
// (128 h-rows). h exchanged as LLC-homed tagged dwords (tag<<16 | bf16), 3-buffer
// rotation; the detecting load IS the data load. No flags, no fences, no atomics.
// TWO barriers/step: trailing barrier re-synchronizes waves each step (minimizes
// spin-round quantization jitter — removing it cost +62%, R17) and drains stores
// off the poll path. This is the measured optimum of the LLC-exchange family
// (R2 flag+data 6.7us/step, R13 barrier-free 7.9, R17 one-barrier 9.0, this 5.5).
// Wh via opaque volatile-asm loads, early-clobber outputs (R9 fault fix).
// Spins BOUNDED (8192): wrong data on timeout, never a hang.
__global__ __launch_bounds__(512, 2)
void scan_kernel(const unsigned short* __restrict__ Whb,  // bf16 [H][H]
                 const unsigned short* __restrict__ xp,   // bf16 [T][B][H]
                 unsigned short* __restrict__ hist,       // bf16 [T][B][H]
                 unsigned* __restrict__ tg) {             // tagged [3][B][H]
  __shared__ unsigned short panel[16 * 1024];  // [16 batches][1024 K], XOR-swizzled

  const int tid = threadIdx.x;
  const int g = blockIdx.x >> 3;
  const int r = blockIdx.x & 7;
  const int wave = tid >> 6;
  const int lane = tid & 63;
  const int nloc = lane & 15;
  const int kgrp = lane >> 4;
  const int hrow = r * 128 + wave * 16 + nloc;   // this lane's h output row
  const int gb0 = g * 16;
  const int xmask = (nloc & 7) << 3;

  // preload Wh fragments via opaque asm loads (non-rematerializable roots).
  bf16x8 wf[32];
  {
    const unsigned short* wb = Whb + (size_t)hrow * Hh + kgrp * 8;
#pragma unroll
    for (int kk = 0; kk < 32; kk += 8) {
      const unsigned short* p = wb + kk * 32;  // 8 frags, 64B apart
      asm volatile(
          "global_load_dwordx4 %0, %8, off\n\t"
          "global_load_dwordx4 %1, %8, off offset:64\n\t"
          "global_load_dwordx4 %2, %8, off offset:128\n\t"
          "global_load_dwordx4 %3, %8, off offset:192\n\t"
          "global_load_dwordx4 %4, %8, off offset:256\n\t"
          "global_load_dwordx4 %5, %8, off offset:320\n\t"
          "global_load_dwordx4 %6, %8, off offset:384\n\t"
          "global_load_dwordx4 %7, %8, off offset:448\n\t"
          "s_waitcnt vmcnt(0)"
          : "=&v"(wf[kk + 0]), "=&v"(wf[kk + 1]), "=&v"(wf[kk + 2]), "=&v"(wf[kk + 3]),
            "=&v"(wf[kk + 4]), "=&v"(wf[kk + 5]), "=&v"(wf[kk + 6]), "=&v"(wf[kk + 7])
          : "v"(p)
          : "memory");
    }
  }

  const int sb  = tid & 15;   // batch (within group) staged by this thread
  const int kc  = tid >> 4;   // 0..31: its 32-element K chunk
  const int sxs = (sb & 7) << 3;

  for (int t = 0; t < Tt; ++t) {
    const int par = t % 3;
    const int nxt = (t + 1) % 3;

    // xp prefetch (normal cached; drained by the spin's vmcnt(0))
    unsigned short xpv[4];
    const size_t xb = (size_t)t * Bb * Hh + hrow;
#pragma unroll
    for (int i = 0; i < 4; ++i) xpv[i] = xp[xb + (size_t)(gb0 + kgrp * 4 + i) * Hh];

    // poll my 32-word chunk of h^{t-1} until every word carries tag t-1.
    // BOUNDED: give up after 8192 rounds -> wrong data, never a hang.
    const unsigned exp = ((unsigned)t - 1u) & 0xFFFFu;
    const unsigned* src = tg + (size_t)par * TGSZ + (size_t)(gb0 + sb) * Hh + kc * 32;
    uint4 d0, d1, d2, d3, d4, d5, d6, d7;
    unsigned bad;
    int tries = 8192;
    do {
      asm volatile(
          "global_load_dwordx4 %0, %8, off sc0 sc1\n\t"
          "global_load_dwordx4 %1, %8, off offset:16 sc0 sc1\n\t"
          "global_load_dwordx4 %2, %8, off offset:32 sc0 sc1\n\t"
          "global_load_dwordx4 %3, %8, off offset:48 sc0 sc1\n\t"
          "global_load_dwordx4 %4, %8, off offset:64 sc0 sc1\n\t"
          "global_load_dwordx4 %5, %8, off offset:80 sc0 sc1\n\t"
          "global_load_dwordx4 %6, %8, off offset:96 sc0 sc1\n\t"
          "global_load_dwordx4 %7, %8, off offset:112 sc0 sc1\n\t"
          "s_waitcnt vmcnt(0)"
          : "=&v"(d0), "=&v"(d1), "=&v"(d2), "=&v"(d3),
            "=&v"(d4), "=&v"(d5), "=&v"(d6), "=&v"(d7)
          : "v"(src) : "memory");
      bad = 0;
#define CHK(v) bad |= ((v.x >> 16) ^ exp) | ((v.y >> 16) ^ exp) | \
                      ((v.z >> 16) ^ exp) | ((v.w >> 16) ^ exp)
      CHK(d0); CHK(d1); CHK(d2); CHK(d3); CHK(d4); CHK(d5); CHK(d6); CHK(d7);
#undef CHK
    } while (bad && --tries);

    // strip tags, pack to bf16 pairs, write swizzled LDS panel
    {
#define PK(a, b) (((a) & 0xFFFFu) | ((b) << 16))
      uint4 p0 = { PK(d0.x, d0.y), PK(d0.z, d0.w), PK(d1.x, d1.y), PK(d1.z, d1.w) };
      uint4 p1 = { PK(d2.x, d2.y), PK(d2.z, d2.w), PK(d3.x, d3.y), PK(d3.z, d3.w) };
      uint4 p2 = { PK(d4.x, d4.y), PK(d4.z, d4.w), PK(d5.x, d5.y), PK(d5.z, d5.w) };
      uint4 p3 = { PK(d6.x, d6.y), PK(d6.z, d6.w), PK(d7.x, d7.y), PK(d7.z, d7.w) };
#undef PK
      const int pb = sb * 1024, k0 = kc * 32;
      *(uint4*)&panel[pb + ((k0)      ^ sxs)] = p0;
      *(uint4*)&panel[pb + ((k0 + 8)  ^ sxs)] = p1;
      *(uint4*)&panel[pb + ((k0 + 16) ^ sxs)] = p2;
      *(uint4*)&panel[pb + ((k0 + 24) ^ sxs)] = p3;
    }
    __syncthreads();

    // MFMA: [16 batch] x [16 rows] over K=1024 (wf held resident by opaque defs)
    f32x4 acc0 = {0.f, 0.f, 0.f, 0.f}, acc1 = {0.f, 0.f, 0.f, 0.f};
#pragma unroll
    for (int kk = 0; kk < 32; kk += 2) {
      bf16x8 a0 = *(const bf16x8*)&panel[nloc * 1024 + ((kk * 32 + kgrp * 8) ^ xmask)];
      bf16x8 a1 = *(const bf16x8*)&panel[nloc * 1024 + (((kk + 1) * 32 + kgrp * 8) ^ xmask)];
      acc0 = mfma16(a0, wf[kk], acc0);
      acc1 = mfma16(a1, wf[kk + 1], acc1);
    }
    f32x4 acc = acc0 + acc1;

    // epilogue: sigmoid, publish tagged h^{t} into buf[(t+1)%3], record history
    const size_t tb = (size_t)t * Bb * Hh;
    unsigned* dbase = tg + (size_t)nxt * TGSZ + hrow;
#pragma unroll
    for (int i = 0; i < 4; ++i) {
      const int mb = gb0 + kgrp * 4 + i;
      float pre = acc[i] + bf2f(xpv[i]);
      float h = 1.0f / (1.0f + __expf(-pre));
      unsigned short hb = f2bf(h);
      unsigned word = ((unsigned)t << 16) | (unsigned)hb;
      asm volatile("global_store_dword %0, %1, off sc0 sc1"
                   :: "v"(dbase + (size_t)mb * Hh), "v"(word) : "memory");
      hist[tb + (size_t)mb * Hh + hrow] = hb;
    }

    // trailing barrier: re-synchronize waves (kills spin-round jitter) and
    // protect the LDS panel from next iteration's staging
    __syncthreads();
  }
}

// ---------------- launch ----------------
extern "C" void kernel_launch(void* const* d_in, const int* in_sizes, int n_in,
                              void* d_out, int out_size, void* d_ws, size_t ws_size,
                              hipStream_t stream) {
  const float* x    = (const float*)d_in[0];
  const float* Wh_w = (const float*)d_in[1];
  const float* Wh_b = (const float*)d_in[2];
  const float* Wx_w = (const float*)d_in[3];
  const float* Wx_b = (const float*)d_in[4];
  const float* Wy_w = (const float*)d_in[5];
  const float* Wy_b = (const float*)d_in[6];

  char* ws = (char*)d_ws;
  constexpr size_t XP_OFF   = 0;                                     // bf16 [T][B][H] = 64 MiB
  constexpr size_t HIST_OFF = XP_OFF   + (size_t)Tt * Bb * Hh * 2;   // 64 MiB
  constexpr size_t WH_OFF   = HIST_OFF + (size_t)Tt * Bb * Hh * 2;   // 2 MiB
  constexpr size_t TG_OFF   = WH_OFF   + (size_t)Hh * Hh * 2;        // 384 KiB

  unsigned short* xp   = (unsigned short*)(ws + XP_OFF);
  unsigned short* hist = (unsigned short*)(ws + HIST_OFF);
  unsigned short* whb  = (unsigned short*)(ws + WH_OFF);
  unsigned*       tg   = (unsigned*)(ws + TG_OFF);

  // tagged-buffer init (fully rewrites all 3 slots every call — no memset needed)
  init_tags<<<dim3((3 * TGSZ) / 256), dim3(256), 0, stream>>>(tg);

  // Wh fp32 -> bf16
  cvt4_kernel<<<dim3((Hh * Hh) / (256 * 4)), dim3(256), 0, stream>>>(Wh_w, whb);

  // xp = x @ Wx^T + Wx_b + Wh_b   (stored [T][B][H] bf16)
  gemm_kernel<0><<<dim3((Bb * Tt) / 64, Hh / 64), dim3(256), 0, stream>>>(
      (const void*)x, Wx_w, Wx_b, Wh_b, (void*)xp);

  // sequential scan (cooperative: all 16 blocks co-resident)
  {
    void* sargs[4] = { (void*)&whb, (void*)&xp, (void*)&hist, (void*)&tg };
    hipLaunchCooperativeKernel((const void*)scan_kernel, dim3(16), dim3(512), sargs, 0, stream);
  }

  // out = hist @ Wy^T + Wy_b  (fp32 [B][T][Do])
  gemm_kernel<1><<<dim3((Bb * Tt) / 64, Do / 64), dim3(256), 0, stream>>>(
      (const void*)hist, Wy_w, Wy_b, nullptr, d_out);
}